// Round 8
// baseline (322.547 us; speedup 1.0000x reference)
//
#include <hip/hip_runtime.h>
#include <float.h>
#include <math.h>

// Problem constants (from reference setup_inputs)
#define B_   32
#define D_   128
#define T_   2048
#define K_   2048
#define N_   (B_ * T_)      // 65536

typedef _Float16 f16;
typedef f16   f16x8 __attribute__((ext_vector_type(8)));
typedef f16   f16x4 __attribute__((ext_vector_type(4)));
typedef f16   f16x2 __attribute__((ext_vector_type(2)));
typedef float f32x4 __attribute__((ext_vector_type(4)));

// async global->LDS, 16 B per lane, LDS dst = wave-uniform base + lane*16
__device__ __forceinline__ void load_lds16(const void* g, void* l) {
    __builtin_amdgcn_global_load_lds(
        (const __attribute__((address_space(1))) unsigned int*)g,
        (__attribute__((address_space(3))) unsigned int*)l, 16, 0, 0);
}

// ---------------------------------------------------------------------------
// Fused prep: blocks 0..1023 transpose/split z -> zh/zl; blocks 1024..1535
// split emb -> eh/el + halfnorm (4 codes per block) and zero cnt/scalars/
// sum_new. One launch instead of two.
// ---------------------------------------------------------------------------
__global__ __launch_bounds__(256)
void prep_all(const float* __restrict__ z, const float* __restrict__ emb,
              f16* __restrict__ zh, f16* __restrict__ zl,
              f16* __restrict__ eh, f16* __restrict__ el,
              float* __restrict__ hn, int* __restrict__ cnt,
              float* __restrict__ scalars, float* __restrict__ sum_new) {
    const int tid = threadIdx.x;
    const int blk = blockIdx.x;
    if (blk >= 1024) {
        // ---- eprep half: 4 codes per block (wave per code) ----
        int k = (blk - 1024) * 4 + (tid >> 6);
        int l = tid & 63;
        if (l == 0) cnt[k] = 0;
        if (blk == 1024 && tid < 4) scalars[tid] = 0.0f;   // loss, ent, dk, done
        sum_new[(size_t)k * D_ + l]      = 0.0f;
        sum_new[(size_t)k * D_ + 64 + l] = 0.0f;
        float a = emb[(size_t)k * D_ + l];
        float b = emb[(size_t)k * D_ + 64 + l];
        f16 ah = (f16)a; f16 al = (f16)(a - (float)ah);
        f16 bh = (f16)b; f16 bl = (f16)(b - (float)bh);
        eh[(size_t)k * D_ + l]      = ah;
        eh[(size_t)k * D_ + 64 + l] = bh;
        el[(size_t)k * D_ + l]      = al;
        el[(size_t)k * D_ + 64 + l] = bl;
        float s = a * a + b * b;
#pragma unroll
        for (int off = 32; off > 0; off >>= 1) s += __shfl_down(s, off, 64);
        if (l == 0) hn[k] = 0.5f * s;
        return;
    }
    // ---- prep half: z [B,D,T] -> row-major fp16 split (transpose via LDS)
    __shared__ float tile[64][129];
    const int b   = blk >> 5;
    const int t0  = (blk & 31) * 64;
    const int n0  = b * T_ + t0;
    const float* zb = z + (size_t)b * D_ * T_ + t0;
#pragma unroll
    for (int it = 0; it < 8; it++) {
        int flat = it * 256 + tid;           // 128 d x 16 q
        int d = flat >> 4;
        int q = flat & 15;
        float4 zv = *(const float4*)(zb + (size_t)d * T_ + q * 4);
        tile[q * 4 + 0][d] = zv.x;
        tile[q * 4 + 1][d] = zv.y;
        tile[q * 4 + 2][d] = zv.z;
        tile[q * 4 + 3][d] = zv.w;
    }
    __syncthreads();
#pragma unroll
    for (int it = 0; it < 8; it++) {
        int r  = it * 8 + (tid >> 5);
        int d0 = (tid & 31) * 4;
        f16x4 hv, lv;
#pragma unroll
        for (int j = 0; j < 4; j++) {
            float v = tile[r][d0 + j];
            f16 hh = (f16)v;
            f16 ll = (f16)(v - (float)hh);
            if (j == 0) { hv.x = hh; lv.x = ll; }
            if (j == 1) { hv.y = hh; lv.y = ll; }
            if (j == 2) { hv.z = hh; lv.z = ll; }
            if (j == 3) { hv.w = hh; lv.w = ll; }
        }
        *(f16x4*)&zh[(size_t)(n0 + r) * D_ + d0] = hv;
        *(f16x4*)&zl[(size_t)(n0 + r) * D_ + d0] = lv;
    }
}

// ---------------------------------------------------------------------------
// MFMA distance-argmin (round-6 verified structure, 123 us / MfmaUtil 37%).
// dot(z,e) = zh.eh + zl.eh + zh.el  (split-fp16, error ~2^-22 |z.e|)
// Block = 64 rows x ALL 2048 codes (kb-loop inside). LDS:
//   AZH/AZL: 64 rows x 128 halves each (16 KB x2, staged ONCE, XOR swizzle)
//   BS:      128 codes x 128 halves (32 KB, streamed per kb: eh tile, el tile)
//   = exactly 64 KB -> 2 blocks/CU (barrier-stall overlap).
// ---------------------------------------------------------------------------
__global__ __launch_bounds__(256, 2)
void argmin_mfma(const f16* __restrict__ zh, const f16* __restrict__ zl,
                 const f16* __restrict__ eh, const f16* __restrict__ el,
                 const float* __restrict__ hn,
                 int* __restrict__ idx, int* __restrict__ cnt, int* __restrict__ pos) {
    __shared__ __align__(16) f16 AZH[64 * 128];   // 16 KB
    __shared__ __align__(16) f16 AZL[64 * 128];   // 16 KB
    __shared__ __align__(16) f16 BS[128 * 128];   // 32 KB

    const int tid = threadIdx.x;
    const int w   = tid >> 6;            // wave 0..3
    const int l   = tid & 63;
    const int wm  = w >> 1;              // row-half (32 rows)
    const int wn  = w & 1;               // code-half (64 codes of the 128-tile)
    const int n0  = blockIdx.x * 64;     // 1024 blocks
    const int c15 = l & 15;
    const int q   = l >> 4;

    // ---- stage A once: 4+4 load_lds16 per wave ----
#pragma unroll
    for (int i = 0; i < 4; i++) {
        int row = w * 16 + i * 4 + q;
        int g   = c15 ^ (row & 15);
        load_lds16(zh + (size_t)(n0 + row) * D_ + g * 8, &AZH[(w * 16 + i * 4) * 128]);
        load_lds16(zl + (size_t)(n0 + row) * D_ + g * 8, &AZL[(w * 16 + i * 4) * 128]);
    }

    float minv[2][4];
    int   mini[2][4];
#pragma unroll
    for (int mi = 0; mi < 2; mi++)
#pragma unroll
        for (int r = 0; r < 4; r++) { minv[mi][r] = FLT_MAX; mini[mi][r] = 0x7fffffff; }

    for (int kb = 0; kb < 16; kb++) {
        const int k0 = kb * 128;
        f32x4 acc[2][4];
#pragma unroll
        for (int mi = 0; mi < 2; mi++)
#pragma unroll
            for (int ni = 0; ni < 4; ni++) acc[mi][ni] = (f32x4){0.f, 0.f, 0.f, 0.f};

        // ---- eh tile: zh.eh + zl.eh ----
        __syncthreads();                 // BS reuse protection
#pragma unroll
        for (int i = 0; i < 8; i++) {
            int cl = w * 32 + i * 4 + q;
            int g  = c15 ^ (cl & 15);
            load_lds16(eh + (size_t)(k0 + cl) * D_ + g * 8, &BS[(w * 32 + i * 4) * 128]);
        }
        __syncthreads();                 // drain (also A on first iter)
#pragma unroll
        for (int s = 0; s < 4; s++) {
            const int gp = (s * 4 + q) ^ c15;
            f16x8 azh[2], azl[2], bf[4];
#pragma unroll
            for (int mi = 0; mi < 2; mi++) {
                int m = wm * 32 + mi * 16 + c15;
                azh[mi] = *(const f16x8*)&AZH[m * 128 + gp * 8];
                azl[mi] = *(const f16x8*)&AZL[m * 128 + gp * 8];
            }
#pragma unroll
            for (int ni = 0; ni < 4; ni++) {
                int n = wn * 64 + ni * 16 + c15;
                bf[ni] = *(const f16x8*)&BS[n * 128 + gp * 8];
            }
#pragma unroll
            for (int mi = 0; mi < 2; mi++)
#pragma unroll
                for (int ni = 0; ni < 4; ni++) {
                    acc[mi][ni] = __builtin_amdgcn_mfma_f32_16x16x32_f16(
                        azh[mi], bf[ni], acc[mi][ni], 0, 0, 0);
                    acc[mi][ni] = __builtin_amdgcn_mfma_f32_16x16x32_f16(
                        azl[mi], bf[ni], acc[mi][ni], 0, 0, 0);
                }
        }

        // ---- el tile: zh.el ----
        __syncthreads();
#pragma unroll
        for (int i = 0; i < 8; i++) {
            int cl = w * 32 + i * 4 + q;
            int g  = c15 ^ (cl & 15);
            load_lds16(el + (size_t)(k0 + cl) * D_ + g * 8, &BS[(w * 32 + i * 4) * 128]);
        }
        __syncthreads();
#pragma unroll
        for (int s = 0; s < 4; s++) {
            const int gp = (s * 4 + q) ^ c15;
            f16x8 azh[2], bf[4];
#pragma unroll
            for (int mi = 0; mi < 2; mi++) {
                int m = wm * 32 + mi * 16 + c15;
                azh[mi] = *(const f16x8*)&AZH[m * 128 + gp * 8];
            }
#pragma unroll
            for (int ni = 0; ni < 4; ni++) {
                int n = wn * 64 + ni * 16 + c15;
                bf[ni] = *(const f16x8*)&BS[n * 128 + gp * 8];
            }
#pragma unroll
            for (int mi = 0; mi < 2; mi++)
#pragma unroll
                for (int ni = 0; ni < 4; ni++)
                    acc[mi][ni] = __builtin_amdgcn_mfma_f32_16x16x32_f16(
                        azh[mi], bf[ni], acc[mi][ni], 0, 0, 0);
        }

        // ---- running argmin update (codes ascend; strict < = first-min) ----
#pragma unroll
        for (int ni = 0; ni < 4; ni++) {
            int   k = k0 + wn * 64 + ni * 16 + c15;
            float h = hn[k];
#pragma unroll
            for (int mi = 0; mi < 2; mi++)
#pragma unroll
                for (int r = 0; r < 4; r++) {
                    float sc = h - acc[mi][ni][r];
                    if (sc < minv[mi][r]) { minv[mi][r] = sc; mini[mi][r] = k; }
                }
        }
    }

    // ---- single epilogue: cross-lane reduce, write idx + count atomic ----
    __syncthreads();                     // all MFMA/LDS reads done; alias A as red
    float* redv = (float*)AZH;           // [64][2]
    int*   redi = (int*)AZL;
#pragma unroll
    for (int mi = 0; mi < 2; mi++)
#pragma unroll
        for (int r = 0; r < 4; r++) {
            float bv = minv[mi][r];
            int   bi = mini[mi][r];
#pragma unroll
            for (int msk = 1; msk < 16; msk <<= 1) {
                float ov = __shfl_xor(bv, msk, 64);
                int   oi = __shfl_xor(bi, msk, 64);
                if (ov < bv || (ov == bv && oi < bi)) { bv = ov; bi = oi; }
            }
            if (c15 == 0) {
                int row = wm * 32 + mi * 16 + q * 4 + r;
                redv[row * 2 + wn] = bv;
                redi[row * 2 + wn] = bi;
            }
        }
    __syncthreads();
    if (tid < 64) {
        float v0 = redv[tid * 2 + 0]; int i0 = redi[tid * 2 + 0];
        float v1 = redv[tid * 2 + 1]; int i1 = redi[tid * 2 + 1];
        if (v1 < v0 || (v1 == v0 && i1 < i0)) { v0 = v1; i0 = i1; }
        int n = n0 + tid;
        idx[n] = i0;
        pos[n] = atomicAdd(&cnt[i0], 1);     // fused assign
    }
}

// ---------------------------------------------------------------------------
// Exclusive prefix sum over 2048 counts, single block of 256 threads.
// ---------------------------------------------------------------------------
__global__ __launch_bounds__(256)
void scan_kernel(const int* __restrict__ cnt, int* __restrict__ offs) {
    __shared__ int part[256];
    const int tid = threadIdx.x;
    int loc[8];
    int s = 0;
#pragma unroll
    for (int j = 0; j < 8; j++) { loc[j] = s; s += cnt[tid * 8 + j]; }
    part[tid] = s;
    __syncthreads();
    for (int off = 1; off < 256; off <<= 1) {
        int v = (tid >= off) ? part[tid - off] : 0;
        __syncthreads();
        part[tid] += v;
        __syncthreads();
    }
    int pre = (tid == 0) ? 0 : part[tid - 1];
#pragma unroll
    for (int j = 0; j < 8; j++) offs[tid * 8 + j] = pre + loc[j];
    if (tid == 255) offs[2048] = pre + s;    // == N
}

// ---------------------------------------------------------------------------
// STE output + loss + fused bucket scatter. Block = 64 t x 128 d of one b.
// The block's 64 codebook rows are staged into LDS (stride-129 pad: reads
// are 2-way aliased = free) via coalesced float4, replacing 8.4M scattered
// scalar L2 gathers with 2M coalesced float4 loads.
// ---------------------------------------------------------------------------
__global__ __launch_bounds__(256)
void ste_kernel(const float* __restrict__ z, const float* __restrict__ emb,
                const int* __restrict__ idx, const int* __restrict__ pos,
                const int* __restrict__ offs, float* __restrict__ out0,
                int* __restrict__ row_list, float* __restrict__ s_loss) {
    __shared__ int   scode[64];
    __shared__ float semb[64][129];          // 32.25 KB
    __shared__ float red[256];
    const int tid = threadIdx.x;
    const int blk = blockIdx.x;              // 1024
    const int b   = blk >> 5;
    const int t0  = (blk & 31) * 64;
    const int n0  = b * T_ + t0;
    if (tid < 64) {
        int n = n0 + tid;
        int code = idx[n];
        scode[tid] = code;
        row_list[offs[code] + pos[n]] = n;   // fused bucket
    }
    __syncthreads();
    // stage the 64 emb rows: 8 float4 per thread, coalesced along d
#pragma unroll
    for (int i = 0; i < 8; i++) {
        int flat = i * 256 + tid;            // 64 rows x 32 dq
        int row = flat >> 5;
        int dq  = flat & 31;
        float4 e4 = *(const float4*)(emb + (size_t)scode[row] * D_ + dq * 4);
        semb[row][dq * 4 + 0] = e4.x;
        semb[row][dq * 4 + 1] = e4.y;
        semb[row][dq * 4 + 2] = e4.z;
        semb[row][dq * 4 + 3] = e4.w;
    }
    __syncthreads();

    const float* zb = z    + (size_t)b * D_ * T_ + t0;
    float*       ob = out0 + (size_t)b * D_ * T_ + t0;
    float lsum = 0.0f;
#pragma unroll
    for (int it = 0; it < 8; it++) {
        int flat = it * 256 + tid;
        int d = flat >> 4;
        int q = flat & 15;
        float4 zv = *(const float4*)(zb + (size_t)d * T_ + q * 4);
        float zi[4] = {zv.x, zv.y, zv.z, zv.w};
        float ov[4];
#pragma unroll
        for (int j = 0; j < 4; j++) {
            float e  = semb[q * 4 + j][d];
            float df = e - zi[j];            // z_vq - zf (one rounding)
            ov[j] = zi[j] + df;              // zf + (z_vq - zf), matches reference STE
            lsum += df * df;
        }
        float4 o4 = {ov[0], ov[1], ov[2], ov[3]};
        *(float4*)(ob + (size_t)d * T_ + q * 4) = o4;
    }

    red[tid] = lsum;
    __syncthreads();
    for (int s = 128; s > 0; s >>= 1) {
        if (tid < s) red[tid] += red[tid + s];
        __syncthreads();
    }
    if (tid == 0) atomicAdd(s_loss, red[0]);
}

// ---------------------------------------------------------------------------
// Segment sum, balanced by ROW: wave per 64 consecutive row_list entries
// (code-sorted). Lane l owns d-pair {2l,2l+1}; wave walks rows via shfl
// broadcast; flushes partials with 2 fp32 atomics/lane at code boundaries.
// ---------------------------------------------------------------------------
__global__ __launch_bounds__(64)
void segsum_kernel(const f16* __restrict__ zh, const f16* __restrict__ zl,
                   const int* __restrict__ row_list, const int* __restrict__ idx,
                   float* __restrict__ sum_new) {
    const int l = threadIdx.x;           // 64
    const int base = blockIdx.x * 64;    // 1024 blocks
    int myrow  = row_list[base + l];
    int mycode = idx[myrow];
    float ax = 0.0f, ay = 0.0f;
    int cur = __shfl(mycode, 0, 64);
#pragma unroll 8
    for (int i = 0; i < 64; i++) {
        int r = __shfl(myrow, i, 64);
        int c = __shfl(mycode, i, 64);
        if (c != cur) {                  // wave-uniform branch
            atomicAdd(&sum_new[(size_t)cur * D_ + l * 2],     ax);
            atomicAdd(&sum_new[(size_t)cur * D_ + l * 2 + 1], ay);
            ax = 0.0f; ay = 0.0f; cur = c;
        }
        f16x2 hv = *(const f16x2*)&zh[(size_t)r * D_ + l * 2];
        f16x2 lv = *(const f16x2*)&zl[(size_t)r * D_ + l * 2];
        ax += (float)hv.x + (float)lv.x;
        ay += (float)hv.y + (float)lv.y;
    }
    atomicAdd(&sum_new[(size_t)cur * D_ + l * 2],     ax);
    atomicAdd(&sum_new[(size_t)cur * D_ + l * 2 + 1], ay);
}

// ---------------------------------------------------------------------------
// EMA update + fused finalization: the LAST block (device-scope done counter)
// reads the scalar accumulators coherently (atomicAdd(p,0)) and writes the
// three scalar outputs — deletes the final_kernel launch.
// ---------------------------------------------------------------------------
__global__ __launch_bounds__(256)
void update_kernel(const float* __restrict__ emb, const float* __restrict__ emb_sum,
                   const float* __restrict__ emb_elem, const float* __restrict__ emb_rand,
                   const float* __restrict__ sum_new, const int* __restrict__ offs,
                   float* __restrict__ out_emb_new, float* __restrict__ out_emb_sum_n,
                   float* __restrict__ out_emb_elem_n,
                   float* __restrict__ scalars, int* __restrict__ done,
                   float* __restrict__ out_loss, float* __restrict__ out_ent,
                   float* __restrict__ out_dk) {
    const float MU  = 0.99f;
    const float OMM = (float)(1.0 - 0.99);   // match JAX's fp64 1.0-0.99 -> fp32
    int gid = blockIdx.x * 256 + threadIdx.x;   // < K_*D_ = 262144
    int k = gid >> 7;
    int d = gid & 127;

    float sn = sum_new[gid];
    float es = emb_sum[gid];
    float en = (float)(offs[k + 1] - offs[k]);
    float ee = emb_elem[k];
    float esn = MU * es + OMM * sn;
    float een = MU * ee + OMM * en;
    out_emb_sum_n[gid] = esn;
    float enew = (een >= 1.0f) ? (esn / een) : emb_rand[gid];
    out_emb_new[gid] = enew;

    float df = enew - emb[gid];
    float v  = df * df;
    __shared__ float red[256];
    red[threadIdx.x] = v;
    __syncthreads();
    for (int s = 128; s > 0; s >>= 1) {
        if (threadIdx.x < s) red[threadIdx.x] += red[threadIdx.x + s];
        __syncthreads();
    }
    if (threadIdx.x == 0) atomicAdd(&scalars[2], red[0]);   // s_dk

    if (d == 0) {
        out_emb_elem_n[k] = een;
        float p = en * (1.0f / 65536.0f);   // sum(elem_new) == N exactly in fp32
        atomicAdd(&scalars[1], p * logf(p + 1e-8f));        // s_ent
    }

    __syncthreads();                     // block's atomics all issued
    if (threadIdx.x == 0) {
        __threadfence();
        int prev = atomicAdd(done, 1);
        if (prev == (int)gridDim.x - 1) {
            float L  = atomicAdd(&scalars[0], 0.0f);        // coherent reads
            float E  = atomicAdd(&scalars[1], 0.0f);
            float Dk = atomicAdd(&scalars[2], 0.0f);
            out_loss[0] = L;
            out_ent[0]  = expf(-E);
            out_dk[0]   = sqrtf(Dk) * (1.0f / 512.0f);      // sqrt(K*D) = 512
        }
    }
}

// ---------------------------------------------------------------------------
extern "C" void kernel_launch(void* const* d_in, const int* in_sizes, int n_in,
                              void* d_out, int out_size, void* d_ws, size_t ws_size,
                              hipStream_t stream) {
    (void)in_sizes; (void)n_in; (void)out_size; (void)ws_size;

    const float* z        = (const float*)d_in[0];   // [32,128,2048]
    const float* emb      = (const float*)d_in[1];   // [2048,128]
    const float* emb_sum  = (const float*)d_in[2];   // [2048,128]
    const float* emb_elem = (const float*)d_in[3];   // [2048]
    const float* emb_rand = (const float*)d_in[4];   // [2048,128]

    float* out = (float*)d_out;
    float* out0            = out;                            // z_vq_out  8388608
    float* out_loss        = out + 8388608;                  // scalar
    float* out_emb_new     = out + 8388609;                  // 262144
    float* out_emb_sum_n   = out + 8388609 + 262144;         // 262144
    float* out_emb_elem_n  = out + 8388609 + 524288;         // 2048
    float* out_ent         = out + 8388609 + 524288 + 2048;  // scalar
    float* out_dk          = out_ent + 1;                    // scalar

    float* ws = (float*)d_ws;                     // offsets in floats
    f16*   zh       = (f16*)(ws);                 // 8388608 halves (4194304 f)
    f16*   zl       = (f16*)(ws + 4194304);       // 8388608 halves
    int*   idx      = (int*)(ws + 8388608);       // 65536
    float* hn       = ws + 8454144;               // 2048
    f16*   eh       = (f16*)(ws + 8456192);       // 262144 halves (131072 f)
    f16*   el       = (f16*)(ws + 8587264);       // 262144 halves
    float* sum_new  = ws + 8718336;               // 262144
    int*   cnt      = (int*)(ws + 8980480);       // 2048
    float* scalars  = ws + 8982528;               // s_loss, s_ent, s_dk, done
    int*   done     = (int*)(scalars + 3);
    int*   pos      = (int*)(ws + 8982532);       // 65536
    int*   offs     = (int*)(ws + 9048068);       // 2049
    int*   row_list = (int*)(ws + 9050117);       // 65536
                                                  // end 9115653 f ~ 36.5 MB

    prep_all<<<1536, 256, 0, stream>>>(z, emb, zh, zl, eh, el, hn, cnt, scalars, sum_new);
    argmin_mfma<<<N_ / 64, 256, 0, stream>>>(zh, zl, eh, el, hn, idx, cnt, pos);
    scan_kernel<<<1, 256, 0, stream>>>(cnt, offs);
    ste_kernel<<<B_ * (T_ / 64), 256, 0, stream>>>(z, emb, idx, pos, offs, out0,
                                                   row_list, scalars /*s_loss*/);
    segsum_kernel<<<N_ / 64, 64, 0, stream>>>(zh, zl, row_list, idx, sum_new);
    update_kernel<<<(K_ * D_) / 256, 256, 0, stream>>>(emb, emb_sum, emb_elem, emb_rand,
                                                       sum_new, offs,
                                                       out_emb_new, out_emb_sum_n,
                                                       out_emb_elem_n, scalars, done,
                                                       out_loss, out_ent, out_dk);
}